// Round 17
// baseline (28.909 us; speedup 1.0000x reference)
//
#include <hip/hip_runtime.h>
#include <hip/hip_bf16.h>
#include <math.h>

// y[n,o] = min_i (x[n,i] + w[o,i]) + bias[o]
// x: (32768,128) f32, w: (128,128) f32, bias: (128,) f32, out: (32768,128) f32
//
// Max-reuse config: 256 threads, BM=BN=128, 8x8 per-thread tile (64 outputs).
// LDS reads per thread per kc = 16 for 512 pk-VALU -> per-CU totals:
// LDS 1024 insts (5.1us) < VALU 6.8us -- first config with LDS strictly
// under the VALU floor. Grid 256 (1 block/CU), no TLP (R11: TLP is not the
// limiter), 64 independent acc chains of ILP, zero barriers in the k-loop.
// f16 tiles, 256B rows, XOR swizzle byte^=(row&7)<<4.

typedef __fp16 h2 __attribute__((ext_vector_type(2)));
typedef __fp16 h4 __attribute__((ext_vector_type(4)));
typedef __fp16 h8 __attribute__((ext_vector_type(8)));

constexpr int K  = 128;
constexpr int BM = 128;

__global__ __launch_bounds__(256)
void minplus_kernel(const float* __restrict__ x,
                    const float* __restrict__ w,
                    const float* __restrict__ bias,
                    float* __restrict__ out)
{
    __shared__ char lds[65536];              // x: [0,32768), w: [32768,65536)

    const int tid = threadIdx.x;
    const float* xsrc = x + (size_t)blockIdx.x * BM * K;

    // ---- stage x (128x128) and w (128x128), f32 -> f16, swizzled ----
    #pragma unroll
    for (int p = 0; p < 16; ++p) {
        int c   = p * 256 + tid;             // float4-chunk id, 0..4095
        int row = c >> 5;                    // 0..127
        int q   = c & 31;
        float4 v = *(const float4*)(xsrc + row * K + q * 4);
        h2 a = __builtin_amdgcn_cvt_pkrtz(v.x, v.y);
        h2 b = __builtin_amdgcn_cvt_pkrtz(v.z, v.w);
        int byte = row * 256 + ((q * 8) ^ ((row & 7) << 4));
        *(h4*)(lds + byte) = __builtin_shufflevector(a, b, 0, 1, 2, 3);
    }
    #pragma unroll
    for (int p = 0; p < 16; ++p) {
        int c   = p * 256 + tid;
        int row = c >> 5;
        int q   = c & 31;
        float4 v = *(const float4*)(w + row * K + q * 4);
        h2 a = __builtin_amdgcn_cvt_pkrtz(v.x, v.y);
        h2 b = __builtin_amdgcn_cvt_pkrtz(v.z, v.w);
        int byte = 32768 + row * 256 + ((q * 8) ^ ((row & 7) << 4));
        *(h4*)(lds + byte) = __builtin_shufflevector(a, b, 0, 1, 2, 3);
    }
    __syncthreads();                         // the ONLY barrier

    const int ty  = tid >> 4;                // 0..15 : rows ty + 16m, m=0..7
    const int tx  = tid & 15;                // 0..15 : cols tx + 16n, n=0..7
    const int swx = (ty & 7) << 4;           // (ty+16m)&7 == ty&7
    const int sww = (tx & 7) << 4;
    const char* xb = lds + ty * 256;
    const char* wb = lds + 32768 + tx * 256;

    h2 hbig;
    hbig.x = (__fp16)65504.0f;
    hbig.y = (__fp16)65504.0f;
    h2 acc[8][8];
    #pragma unroll
    for (int m = 0; m < 8; ++m)
        #pragma unroll
        for (int n = 0; n < 8; ++n)
            acc[m][n] = hbig;

    // ---- 16 chunks of 8 k-elems: 16 ds_read_b128 + 512 pk-VALU each ----
    #pragma unroll 2
    for (int kc = 0; kc < 16; ++kc) {
        const char* xr = xb + ((kc * 16) ^ swx);   // 1 v_xor
        const char* wr = wb + ((kc * 16) ^ sww);   // 1 v_xor
        h8 xv0 = *(const h8*)(xr + 0 * 4096);
        h8 xv1 = *(const h8*)(xr + 1 * 4096);
        h8 xv2 = *(const h8*)(xr + 2 * 4096);
        h8 xv3 = *(const h8*)(xr + 3 * 4096);
        h8 xv4 = *(const h8*)(xr + 4 * 4096);
        h8 xv5 = *(const h8*)(xr + 5 * 4096);
        h8 xv6 = *(const h8*)(xr + 6 * 4096);
        h8 xv7 = *(const h8*)(xr + 7 * 4096);
        h8 wv0 = *(const h8*)(wr + 0 * 4096);
        h8 wv1 = *(const h8*)(wr + 1 * 4096);
        h8 wv2 = *(const h8*)(wr + 2 * 4096);
        h8 wv3 = *(const h8*)(wr + 3 * 4096);
        h8 wv4 = *(const h8*)(wr + 4 * 4096);
        h8 wv5 = *(const h8*)(wr + 5 * 4096);
        h8 wv6 = *(const h8*)(wr + 6 * 4096);
        h8 wv7 = *(const h8*)(wr + 7 * 4096);

#define UPD(m, n, XV, WV)                                                     \
        {                                                                     \
            h8 t  = XV + WV;                 /* 4x v_pk_add_f16 */            \
            h2 t0 = __builtin_shufflevector(t, t, 0, 1);                      \
            h2 t1 = __builtin_shufflevector(t, t, 2, 3);                      \
            h2 t2 = __builtin_shufflevector(t, t, 4, 5);                      \
            h2 t3 = __builtin_shufflevector(t, t, 6, 7);                      \
            h2 u  = __builtin_elementwise_min(t0, t1);                        \
            h2 v  = __builtin_elementwise_min(t2, t3);                        \
            h2 uv = __builtin_elementwise_min(u, v);                          \
            acc[m][n] = __builtin_elementwise_min(acc[m][n], uv);             \
        }
#define ROW(m, XV)                                                            \
        UPD(m, 0, XV, wv0) UPD(m, 1, XV, wv1) UPD(m, 2, XV, wv2) UPD(m, 3, XV, wv3) \
        UPD(m, 4, XV, wv4) UPD(m, 5, XV, wv5) UPD(m, 6, XV, wv6) UPD(m, 7, XV, wv7)
        ROW(0, xv0) ROW(1, xv1) ROW(2, xv2) ROW(3, xv3)
        ROW(4, xv4) ROW(5, xv5) ROW(6, xv6) ROW(7, xv7)
#undef ROW
#undef UPD
    }

    // ---- epilogue: f16 pair-reduce -> f32, + bias, store ----
    const int rowbase = blockIdx.x * BM + ty;
    #pragma unroll
    for (int n = 0; n < 8; ++n) {
        float b = bias[tx + 16 * n];
        #pragma unroll
        for (int m = 0; m < 8; ++m) {
            h2 a = acc[m][n];
            out[(size_t)(rowbase + 16 * m) * 128 + tx + 16 * n] =
                fminf((float)a.x, (float)a.y) + b;
        }
    }
}

extern "C" void kernel_launch(void* const* d_in, const int* in_sizes, int n_in,
                              void* d_out, int out_size, void* d_ws, size_t ws_size,
                              hipStream_t stream) {
    const float* x    = (const float*)d_in[0];
    const float* w    = (const float*)d_in[1];
    const float* bias = (const float*)d_in[2];
    float* out = (float*)d_out;

    int nrows  = in_sizes[0] / K;            // 32768
    int blocks = nrows / BM;                 // 256 -> 1 block/CU
    minplus_kernel<<<blocks, 256, 0, stream>>>(x, w, bias, out);
}